// Round 6
// baseline (335.760 us; speedup 1.0000x reference)
//
#include <hip/hip_runtime.h>
#include <hip/hip_bf16.h>

typedef __bf16 bf16;
typedef __bf16 bf16x8 __attribute__((ext_vector_type(8)));
typedef float  floatx4 __attribute__((ext_vector_type(4)));

#define EPSF    1e-7f
#define MAXNORM 0.99999f   // (1 - 1e-5) / sqrt(C), C = 1
#define TS_LD   136        // padded leading dim for LDS intermediate tile

// rowwise scale implementing logmap0(proj(expmap0(h))) = scale(||h||) * h
__device__ __forceinline__ float hyp_scale(float ss) {
    float n  = sqrtf(ss);
    float nh = fmaxf(n, EPSF);
    float s1 = tanhf(nh) / nh;
    float nx = s1 * n;
    if (nx > MAXNORM) { s1 *= MAXNORM / nx; nx = MAXNORM; }
    float nx2 = fmaxf(nx, EPSF);
    return (atanhf(nx2) / nx2) * s1;
}

__device__ __forceinline__ bf16x8 cvt8(float4 a, float4 b) {
    bf16x8 r;
    r[0] = (bf16)a.x; r[1] = (bf16)a.y; r[2] = (bf16)a.z; r[3] = (bf16)a.w;
    r[4] = (bf16)b.x; r[5] = (bf16)b.y; r[6] = (bf16)b.z; r[7] = (bf16)b.w;
    return r;
}

// XOR-granule swizzles (16B granules, conflict-free MFMA frag reads)
__device__ __forceinline__ int sw128(int row, int k) {
    return row * 128 + (((k >> 3) ^ (row & 15)) << 3) + (k & 7);
}
__device__ __forceinline__ int sw64(int row, int k) {
    return row * 64 + (((k >> 3) ^ (row & 7)) << 3) + (k & 7);
}

// ---------------------------------------------------------------------------
// MTP layout: granule G = ((b*16 + kk)*128 + n)*8 + gp (16B, n-major), holding
// m[node = kk*64 + (gp^(n&7))*8 + j][dim = n], j=0..7.  This is the sw64 byte
// image, so sw64(n,k) indexes it DIRECTLY in global memory — the K-loop loads
// MFMA fragments straight to VGPRs with no LDS staging at all.
// AdjB is the same image for Adj rows: tile (b,mt) + kk*8192 + sw64(row,k).
// ---------------------------------------------------------------------------

// ---------------------------------------------------------------------------
// pack_adj: Adj fp32 -> AdjB bf16 block-tiled pre-swizzled (sequential both
// sides, permutation via LDS).  (verified)
// ---------------------------------------------------------------------------
__global__ __launch_bounds__(256) void pack_adj(
    const float* __restrict__ Adj, bf16* __restrict__ AdjB)
{
    __shared__ __align__(16) bf16 Ls[4096 * 8];   // 64 KB, output-ordered granules
    const int tid = threadIdx.x, bp = blockIdx.x;
    const int bmt = bp >> 2, q = bp & 3;          // q = row-quarter (32 rows)
    const float* src = Adj + ((size_t)bmt << 17) + ((size_t)q << 15);

    #pragma unroll
    for (int i = 0; i < 16; ++i) {
        int gi = i * 256 + tid;                   // input granule, row-major
        int row = gi >> 7, gcol = gi & 127;
        int kk = gcol >> 3, gp = gcol & 7;
        const float4* p = reinterpret_cast<const float4*>(src + ((size_t)gi << 3));
        float4 v0 = p[0], v1 = p[1];
        int gpp = gp ^ (row & 7);                 // (q*32+row)&7 == row&7
        *reinterpret_cast<bf16x8*>(&Ls[((kk * 32 + row) * 8 + gpp) * 8]) = cvt8(v0, v1);
    }
    __syncthreads();

    bf16* dst = AdjB + ((size_t)bmt << 17);
    #pragma unroll
    for (int i = 0; i < 16; ++i) {
        int go = i * 256 + tid;
        int kk = go >> 8, rem = go & 255;
        *reinterpret_cast<bf16x8*>(&dst[((((size_t)kk << 10) + (q << 8) + rem)) << 3]) =
            *reinterpret_cast<const bf16x8*>(&Ls[go * 8]);
    }
}

// ---------------------------------------------------------------------------
// K1: embed + msg0 fused.  Per block: 128 rows.  (verified, unchanged)
// ---------------------------------------------------------------------------
__global__ __launch_bounds__(256) void embed_msg(
    const float* __restrict__ X, const float* __restrict__ Wemb,
    const float* __restrict__ Wmsg, const float* __restrict__ bmsg,
    bf16* __restrict__ M, bf16* __restrict__ MT)
{
    __shared__ __align__(16) bf16 Xs[128 * 128];
    __shared__ __align__(16) bf16 Ws[128 * 128];
    __shared__ __align__(16) bf16 W2[128 * 128];   // reused as Ts2 after phase 2
    __shared__ __align__(16) bf16 Ts[128 * TS_LD];
    const int tid = threadIdx.x, bx = blockIdx.x;

    {
        const float4* Xg = reinterpret_cast<const float4*>(X + (size_t)bx * 16384);
        #pragma unroll
        for (int i = 0; i < 8; ++i) {
            int g = tid + i * 256, row = g >> 4, gc = g & 15;
            float4 v0 = Xg[2 * g], v1 = Xg[2 * g + 1];
            *reinterpret_cast<bf16x8*>(&Xs[row * 128 + ((gc ^ (row & 15)) << 3)]) = cvt8(v0, v1);
        }
    }
    {
        const float4* Wg = reinterpret_cast<const float4*>(Wemb);
        #pragma unroll
        for (int i = 0; i < 8; ++i) {
            int g = tid + i * 256, row = g >> 4, gc = g & 15;
            float4 v0 = Wg[2 * g], v1 = Wg[2 * g + 1];
            *reinterpret_cast<bf16x8*>(&Ws[row * 128 + ((gc ^ (row & 15)) << 3)]) = cvt8(v0, v1);
        }
    }
    {
        const int c0 = (tid & 15) * 8;
        #pragma unroll
        for (int rr = 0; rr < 8; ++rr) {
            int r = (tid >> 4) * 8 + rr;
            const float4* p = reinterpret_cast<const float4*>(Wmsg + r * 128 + c0);
            float4 v0 = p[0], v1 = p[1];
            float vv[8] = {v0.x, v0.y, v0.z, v0.w, v1.x, v1.y, v1.z, v1.w};
            #pragma unroll
            for (int j = 0; j < 8; ++j) {
                int n = c0 + j;
                W2[n * 128 + (((r >> 3) ^ (n & 15)) << 3) + (r & 7)] = (bf16)vv[j];
            }
        }
    }
    __syncthreads();

    const int lane = tid & 63, wv = tid >> 6, n16 = lane & 15, quad = lane >> 4;
    const int rbase = wv * 32;

    floatx4 acc[2][8];
    #pragma unroll
    for (int a = 0; a < 2; ++a)
        #pragma unroll
        for (int c = 0; c < 8; ++c) acc[a][c] = (floatx4){0.f, 0.f, 0.f, 0.f};
    #pragma unroll
    for (int kc = 0; kc < 4; ++kc) {
        int k0 = kc * 32 + quad * 8;
        bf16x8 a0 = *reinterpret_cast<const bf16x8*>(&Xs[sw128(rbase + n16, k0)]);
        bf16x8 a1 = *reinterpret_cast<const bf16x8*>(&Xs[sw128(rbase + 16 + n16, k0)]);
        #pragma unroll
        for (int ct = 0; ct < 8; ++ct) {
            bf16x8 b = *reinterpret_cast<const bf16x8*>(&Ws[sw128(ct * 16 + n16, k0)]);
            acc[0][ct] = __builtin_amdgcn_mfma_f32_16x16x32_bf16(a0, b, acc[0][ct], 0, 0, 0);
            acc[1][ct] = __builtin_amdgcn_mfma_f32_16x16x32_bf16(a1, b, acc[1][ct], 0, 0, 0);
        }
    }
    #pragma unroll
    for (int rt = 0; rt < 2; ++rt) {
        #pragma unroll
        for (int r = 0; r < 4; ++r) {
            int row = rbase + rt * 16 + quad * 4 + r;
            float u[8], ss = 0.f;
            #pragma unroll
            for (int ct = 0; ct < 8; ++ct) { u[ct] = acc[rt][ct][r]; ss += u[ct] * u[ct]; }
            #pragma unroll
            for (int off = 1; off < 16; off <<= 1) ss += __shfl_xor(ss, off);
            float sc = hyp_scale(ss);
            #pragma unroll
            for (int ct = 0; ct < 8; ++ct)
                Ts[row * TS_LD + ct * 16 + n16] = (bf16)(u[ct] * sc);
        }
    }
    __syncthreads();

    floatx4 acc2[2][8];
    #pragma unroll
    for (int a = 0; a < 2; ++a)
        #pragma unroll
        for (int c = 0; c < 8; ++c) acc2[a][c] = (floatx4){0.f, 0.f, 0.f, 0.f};
    #pragma unroll
    for (int kc = 0; kc < 4; ++kc) {
        int k0 = kc * 32 + quad * 8;
        bf16x8 a0 = *reinterpret_cast<const bf16x8*>(&Ts[(rbase + n16) * TS_LD + k0]);
        bf16x8 a1 = *reinterpret_cast<const bf16x8*>(&Ts[(rbase + 16 + n16) * TS_LD + k0]);
        #pragma unroll
        for (int ct = 0; ct < 8; ++ct) {
            bf16x8 b = *reinterpret_cast<const bf16x8*>(&W2[sw128(ct * 16 + n16, k0)]);
            acc2[0][ct] = __builtin_amdgcn_mfma_f32_16x16x32_bf16(a0, b, acc2[0][ct], 0, 0, 0);
            acc2[1][ct] = __builtin_amdgcn_mfma_f32_16x16x32_bf16(a1, b, acc2[1][ct], 0, 0, 0);
        }
    }
    float bv[8];
    #pragma unroll
    for (int ct = 0; ct < 8; ++ct) bv[ct] = bmsg[ct * 16 + n16];
    // pass 1: M row-major from regs (acc2 stays live across the barrier)
    #pragma unroll
    for (int rt = 0; rt < 2; ++rt) {
        #pragma unroll
        for (int r = 0; r < 4; ++r) {
            int lrow = rbase + rt * 16 + quad * 4 + r;
            size_t grow = (size_t)bx * 128 + lrow;
            #pragma unroll
            for (int ct = 0; ct < 8; ++ct)
                M[grow * 128 + ct * 16 + n16] = (bf16)(acc2[rt][ct][r] + bv[ct]);
        }
    }
    __syncthreads();                 // all phase-2 W2 reads done; W2 -> Ts2
    bf16* Ts2 = W2;                  // [128 dims][128 nodes], node XOR-swizzled
    #pragma unroll
    for (int rt = 0; rt < 2; ++rt) {
        #pragma unroll
        for (int r = 0; r < 4; ++r) {
            int lrow = rbase + rt * 16 + quad * 4 + r;
            #pragma unroll
            for (int ct = 0; ct < 8; ++ct) {
                int dim = ct * 16 + n16;
                Ts2[dim * 128 + (lrow ^ ((dim & 7) << 3))] = (bf16)(acc2[rt][ct][r] + bv[ct]);
            }
        }
    }
    __syncthreads();
    // MTP emission: 2048 granules; lane = linear granule -> contiguous 16B LDS
    // reads and fully coalesced stores.  Block owns kk tiles {mt*2, mt*2+1}.
    {
        const size_t tb = (((size_t)(bx >> 3) * 16 + (size_t)(bx & 7) * 2) << 10);
        #pragma unroll
        for (int i = 0; i < 8; ++i) {
            int g = i * 256 + tid;
            int gp = g & 7, n = (g >> 3) & 127, kkl = g >> 10;
            bf16x8 v = *reinterpret_cast<const bf16x8*>(&Ts2[n * 128 + kkl * 64 + gp * 8]);
            *reinterpret_cast<bf16x8*>(MT + ((tb + (size_t)g) << 3)) = v;
        }
    }
}

// ---------------------------------------------------------------------------
// adj_fast v3: BARRIER-FREE K-loop.  sw64 fragment indices applied directly to
// global AdjB/MTP (same byte image the LDS held) -> MFMA operands loaded
// straight into VGPRs, 2-stage register rotation, fully unrolled.  No LDS, no
// s_barrier, no vmcnt discipline in the loop: 16 independent waves/CU hide
// latency by TLP.  LDS = epilogue only (65 KB -> still 2 blocks/CU).
// Epilogue identical to verified R5 version.
// ---------------------------------------------------------------------------
template <int LAST>
__global__ __launch_bounds__(512) void adj_fast(
    const bf16* __restrict__ AdjB, const bf16* __restrict__ MT,
    const bf16* __restrict__ Mprev,
    const float* __restrict__ Wagg, const float* __restrict__ bagg,
    const float* __restrict__ W2f,  const float* __restrict__ b2,
    const float* __restrict__ Mask,
    bf16* __restrict__ Mout, bf16* __restrict__ MTout, float* __restrict__ Out)
{
    __shared__ __align__(16) bf16 smem[33280];    // 65 KB: Ts | Wa | Ts2

    const int tid = threadIdx.x, bid = blockIdx.x;
    const int h = bid >> 8, inner = bid & 255;
    const int mt = inner >> 5, b = inner & 31;
    // A: 64-row half-tile image; B: batch MTP image (both sw64 byte images)
    const bf16* Ab = AdjB + ((size_t)(b * 8 + mt) << 17) + ((size_t)h << 12);
    const bf16* Bg = MT + ((size_t)b << 17);

    const int lane = tid & 63, wv = tid >> 6, n16 = lane & 15, quad = lane >> 4;
    const int wr = (wv >> 2) * 32, wc = (wv & 3) * 32;      // wave = 32 rows x 32 dims

    // per-lane fragment offsets within one kk-tile (elements)
    int offA[2][2], offB[2][2];
    #pragma unroll
    for (int rt = 0; rt < 2; ++rt)
        #pragma unroll
        for (int kc = 0; kc < 2; ++kc)
            offA[rt][kc] = sw64(wr + rt * 16 + n16, kc * 32 + quad * 8);
    #pragma unroll
    for (int ct = 0; ct < 2; ++ct)
        #pragma unroll
        for (int kc = 0; kc < 2; ++kc)
            offB[ct][kc] = sw64(wc + ct * 16 + n16, kc * 32 + quad * 8);

    floatx4 acc[2][2];
    #pragma unroll
    for (int a = 0; a < 2; ++a)
        #pragma unroll
        for (int c = 0; c < 2; ++c) acc[a][c] = (floatx4){0.f, 0.f, 0.f, 0.f};

    bf16x8 af[2][2][2], bf[2][2][2];   // [stage][frag][kc]
    // prologue: load phase 0 into stage 0
    #pragma unroll
    for (int rt = 0; rt < 2; ++rt)
        #pragma unroll
        for (int kc = 0; kc < 2; ++kc) {
            af[0][rt][kc] = *reinterpret_cast<const bf16x8*>(Ab + offA[rt][kc]);
            bf[0][rt][kc] = *reinterpret_cast<const bf16x8*>(Bg + offB[rt][kc]);
        }
    #pragma unroll
    for (int p = 0; p < 16; ++p) {
        const int cur = p & 1, nxt = cur ^ 1;
        if (p + 1 < 16) {
            const bf16* at = Ab + ((size_t)(p + 1) << 13);
            const bf16* bt = Bg + ((size_t)(p + 1) << 13);
            #pragma unroll
            for (int rt = 0; rt < 2; ++rt)
                #pragma unroll
                for (int kc = 0; kc < 2; ++kc) {
                    af[nxt][rt][kc] = *reinterpret_cast<const bf16x8*>(at + offA[rt][kc]);
                    bf[nxt][rt][kc] = *reinterpret_cast<const bf16x8*>(bt + offB[rt][kc]);
                }
        }
        #pragma unroll
        for (int kc = 0; kc < 2; ++kc)
            #pragma unroll
            for (int rt = 0; rt < 2; ++rt)
                #pragma unroll
                for (int ct = 0; ct < 2; ++ct)
                    acc[rt][ct] = __builtin_amdgcn_mfma_f32_16x16x32_bf16(
                        af[cur][rt][kc], bf[cur][ct][kc], acc[rt][ct], 0, 0, 0);
    }
    __syncthreads();   // epilogue LDS about to be written by all waves

    bf16* Ts  = smem;                  // [64][TS_LD] = 8704 elems
    bf16* Wa  = smem + 8704;           // 128x128 sw128 (Wagg, then W2 over it)
    bf16* Ts2 = smem + 25088;          // [128 dims][64 nodes] swizzled (8192)

    // write agg C-tiles into padded Ts
    #pragma unroll
    for (int rt = 0; rt < 2; ++rt)
        #pragma unroll
        for (int ct = 0; ct < 2; ++ct)
            #pragma unroll
            for (int r = 0; r < 4; ++r) {
                int row = wr + rt * 16 + quad * 4 + r, col = wc + ct * 16 + n16;
                Ts[row * TS_LD + col] = (bf16)acc[rt][ct][r];
            }
    // stage Wagg [in][out] transposed -> Wa
    {
        const int c0 = (tid & 15) * 8;
        #pragma unroll
        for (int rr = 0; rr < 4; ++rr) {
            int r = (tid >> 4) * 4 + rr;
            const float4* p = reinterpret_cast<const float4*>(Wagg + r * 128 + c0);
            float4 v0 = p[0], v1 = p[1];
            float vv[8] = {v0.x, v0.y, v0.z, v0.w, v1.x, v1.y, v1.z, v1.w};
            #pragma unroll
            for (int j = 0; j < 8; ++j) {
                int n = c0 + j;
                Wa[n * 128 + (((r >> 3) ^ (n & 15)) << 3) + (r & 7)] = (bf16)vv[j];
            }
        }
    }
    __syncthreads();

    // phase 3 (waves 0-3): u = relu(agg@Wagg + bagg + m_prev); t = rowscale(u)
    const int rbase = (wv & 3) * 16;
    const size_t growbase = (size_t)b * 1024 + (size_t)mt * 128 + (size_t)h * 64;
    floatx4 acc2[8];
    #pragma unroll
    for (int c = 0; c < 8; ++c) acc2[c] = (floatx4){0.f, 0.f, 0.f, 0.f};
    if (wv < 4) {
        #pragma unroll
        for (int kc = 0; kc < 4; ++kc) {
            int k0 = kc * 32 + quad * 8;
            bf16x8 a = *reinterpret_cast<const bf16x8*>(&Ts[(rbase + n16) * TS_LD + k0]);
            #pragma unroll
            for (int ct = 0; ct < 8; ++ct) {
                bf16x8 bb = *reinterpret_cast<const bf16x8*>(&Wa[sw128(ct * 16 + n16, k0)]);
                acc2[ct] = __builtin_amdgcn_mfma_f32_16x16x32_bf16(a, bb, acc2[ct], 0, 0, 0);
            }
        }
        float bva[8];
        #pragma unroll
        for (int ct = 0; ct < 8; ++ct) bva[ct] = bagg[ct * 16 + n16];
        #pragma unroll
        for (int r = 0; r < 4; ++r) {
            int row = rbase + quad * 4 + r;
            size_t grow = growbase + row;
            float u[8], ss = 0.f;
            #pragma unroll
            for (int ct = 0; ct < 8; ++ct) {
                u[ct] = fmaxf(acc2[ct][r] + bva[ct] + (float)Mprev[grow * 128 + ct * 16 + n16], 0.f);
                ss += u[ct] * u[ct];
            }
            #pragma unroll
            for (int off = 1; off < 16; off <<= 1) ss += __shfl_xor(ss, off);
            float sc = hyp_scale(ss);
            #pragma unroll
            for (int ct = 0; ct < 8; ++ct)
                Ts[row * TS_LD + ct * 16 + n16] = (bf16)(u[ct] * sc);
        }
    }
    __syncthreads();   // Wa reads done; load W2 over it

    if (LAST) {
        const float4* Wg = reinterpret_cast<const float4*>(W2f);
        #pragma unroll
        for (int i = 0; i < 4; ++i) {
            int g = tid + i * 512, row = g >> 4, gc = g & 15;
            float4 v0 = Wg[2 * g], v1 = Wg[2 * g + 1];
            *reinterpret_cast<bf16x8*>(&Wa[row * 128 + ((gc ^ (row & 15)) << 3)]) = cvt8(v0, v1);
        }
    } else {
        const int c0 = (tid & 15) * 8;
        #pragma unroll
        for (int rr = 0; rr < 4; ++rr) {
            int r = (tid >> 4) * 4 + rr;
            const float4* p = reinterpret_cast<const float4*>(W2f + r * 128 + c0);
            float4 v0 = p[0], v1 = p[1];
            float vv[8] = {v0.x, v0.y, v0.z, v0.w, v1.x, v1.y, v1.z, v1.w};
            #pragma unroll
            for (int j = 0; j < 8; ++j) {
                int n = c0 + j;
                Wa[n * 128 + (((r >> 3) ^ (n & 15)) << 3) + (r & 7)] = (bf16)vv[j];
            }
        }
    }
    __syncthreads();

    // phase 4 (waves 0-3): t @ W2 (+b2)
    floatx4 acc3[8];
    #pragma unroll
    for (int c = 0; c < 8; ++c) acc3[c] = (floatx4){0.f, 0.f, 0.f, 0.f};
    if (wv < 4) {
        #pragma unroll
        for (int kc = 0; kc < 4; ++kc) {
            int k0 = kc * 32 + quad * 8;
            bf16x8 a = *reinterpret_cast<const bf16x8*>(&Ts[(rbase + n16) * TS_LD + k0]);
            #pragma unroll
            for (int ct = 0; ct < 8; ++ct) {
                bf16x8 bb = *reinterpret_cast<const bf16x8*>(&Wa[sw128(ct * 16 + n16, k0)]);
                acc3[ct] = __builtin_amdgcn_mfma_f32_16x16x32_bf16(a, bb, acc3[ct], 0, 0, 0);
            }
        }
        float bv2[8];
        #pragma unroll
        for (int ct = 0; ct < 8; ++ct) bv2[ct] = b2[ct * 16 + n16];
        #pragma unroll
        for (int r = 0; r < 4; ++r) {
            int row = rbase + quad * 4 + r;
            size_t grow = growbase + row;
            if (LAST) {
                float mk = Mask[grow];
                #pragma unroll
                for (int ct = 0; ct < 8; ++ct)
                    Out[grow * 128 + ct * 16 + n16] = (acc3[ct][r] + bv2[ct]) * mk;
            } else {
                #pragma unroll
                for (int ct = 0; ct < 8; ++ct) {
                    int dim = ct * 16 + n16;
                    bf16 o = (bf16)(acc3[ct][r] + bv2[ct]);
                    Mout[grow * 128 + dim] = o;
                    Ts2[dim * 64 + (row ^ ((dim & 7) << 3))] = o;
                }
            }
        }
    }
    if (!LAST) {
        __syncthreads();
        // MTP emission: this half-block owns kk-tile (mt*2 + h) of batch b.
        const size_t tb = (((size_t)b * 16 + (size_t)(mt * 2 + h)) << 10);
        #pragma unroll
        for (int i = 0; i < 2; ++i) {
            int g = i * 512 + tid;
            int gp = g & 7, n = g >> 3;
            bf16x8 v = *reinterpret_cast<const bf16x8*>(&Ts2[n * 64 + gp * 8]);
            *reinterpret_cast<bf16x8*>(MTout + ((tb + (size_t)g) << 3)) = v;
        }
    }
}

// ---------------------------------------------------------------------------
// Legacy pair (old MT [b][dim][node] layout) — fallback if workspace too small.
// ---------------------------------------------------------------------------
__global__ __launch_bounds__(256) void embed_msg_legacy(
    const float* __restrict__ X, const float* __restrict__ Wemb,
    const float* __restrict__ Wmsg, const float* __restrict__ bmsg,
    bf16* __restrict__ M, bf16* __restrict__ MT)
{
    __shared__ __align__(16) bf16 Xs[128 * 128];
    __shared__ __align__(16) bf16 Ws[128 * 128];
    __shared__ __align__(16) bf16 W2[128 * 128];
    __shared__ __align__(16) bf16 Ts[128 * TS_LD];
    const int tid = threadIdx.x, bx = blockIdx.x;

    {
        const float4* Xg = reinterpret_cast<const float4*>(X + (size_t)bx * 16384);
        #pragma unroll
        for (int i = 0; i < 8; ++i) {
            int g = tid + i * 256, row = g >> 4, gc = g & 15;
            float4 v0 = Xg[2 * g], v1 = Xg[2 * g + 1];
            *reinterpret_cast<bf16x8*>(&Xs[row * 128 + ((gc ^ (row & 15)) << 3)]) = cvt8(v0, v1);
        }
    }
    {
        const float4* Wg = reinterpret_cast<const float4*>(Wemb);
        #pragma unroll
        for (int i = 0; i < 8; ++i) {
            int g = tid + i * 256, row = g >> 4, gc = g & 15;
            float4 v0 = Wg[2 * g], v1 = Wg[2 * g + 1];
            *reinterpret_cast<bf16x8*>(&Ws[row * 128 + ((gc ^ (row & 15)) << 3)]) = cvt8(v0, v1);
        }
    }
    {
        const int c0 = (tid & 15) * 8;
        #pragma unroll
        for (int rr = 0; rr < 8; ++rr) {
            int r = (tid >> 4) * 8 + rr;
            const float4* p = reinterpret_cast<const float4*>(Wmsg + r * 128 + c0);
            float4 v0 = p[0], v1 = p[1];
            float vv[8] = {v0.x, v0.y, v0.z, v0.w, v1.x, v1.y, v1.z, v1.w};
            #pragma unroll
            for (int j = 0; j < 8; ++j) {
                int n = c0 + j;
                W2[n * 128 + (((r >> 3) ^ (n & 15)) << 3) + (r & 7)] = (bf16)vv[j];
            }
        }
    }
    __syncthreads();

    const int lane = tid & 63, wv = tid >> 6, n16 = lane & 15, quad = lane >> 4;
    const int rbase = wv * 32;

    floatx4 acc[2][8];
    #pragma unroll
    for (int a = 0; a < 2; ++a)
        #pragma unroll
        for (int c = 0; c < 8; ++c) acc[a][c] = (floatx4){0.f, 0.f, 0.f, 0.f};
    #pragma unroll
    for (int kc = 0; kc < 4; ++kc) {
        int k0 = kc * 32 + quad * 8;
        bf16x8 a0 = *reinterpret_cast<const bf16x8*>(&Xs[sw128(rbase + n16, k0)]);
        bf16x8 a1 = *reinterpret_cast<const bf16x8*>(&Xs[sw128(rbase + 16 + n16, k0)]);
        #pragma unroll
        for (int ct = 0; ct < 8; ++ct) {
            bf16x8 b = *reinterpret_cast<const bf16x8*>(&Ws[sw128(ct * 16 + n16, k0)]);
            acc[0][ct] = __builtin_amdgcn_mfma_f32_16x16x32_bf16(a0, b, acc[0][ct], 0, 0, 0);
            acc[1][ct] = __builtin_amdgcn_mfma_f32_16x16x32_bf16(a1, b, acc[1][ct], 0, 0, 0);
        }
    }
    #pragma unroll
    for (int rt = 0; rt < 2; ++rt) {
        #pragma unroll
        for (int r = 0; r < 4; ++r) {
            int row = rbase + rt * 16 + quad * 4 + r;
            float u[8], ss = 0.f;
            #pragma unroll
            for (int ct = 0; ct < 8; ++ct) { u[ct] = acc[rt][ct][r]; ss += u[ct] * u[ct]; }
            #pragma unroll
            for (int off = 1; off < 16; off <<= 1) ss += __shfl_xor(ss, off);
            float sc = hyp_scale(ss);
            #pragma unroll
            for (int ct = 0; ct < 8; ++ct)
                Ts[row * TS_LD + ct * 16 + n16] = (bf16)(u[ct] * sc);
        }
    }
    __syncthreads();

    floatx4 acc2[2][8];
    #pragma unroll
    for (int a = 0; a < 2; ++a)
        #pragma unroll
        for (int c = 0; c < 8; ++c) acc2[a][c] = (floatx4){0.f, 0.f, 0.f, 0.f};
    #pragma unroll
    for (int kc = 0; kc < 4; ++kc) {
        int k0 = kc * 32 + quad * 8;
        bf16x8 a0 = *reinterpret_cast<const bf16x8*>(&Ts[(rbase + n16) * TS_LD + k0]);
        bf16x8 a1 = *reinterpret_cast<const bf16x8*>(&Ts[(rbase + 16 + n16) * TS_LD + k0]);
        #pragma unroll
        for (int ct = 0; ct < 8; ++ct) {
            bf16x8 b = *reinterpret_cast<const bf16x8*>(&W2[sw128(ct * 16 + n16, k0)]);
            acc2[0][ct] = __builtin_amdgcn_mfma_f32_16x16x32_bf16(a0, b, acc2[0][ct], 0, 0, 0);
            acc2[1][ct] = __builtin_amdgcn_mfma_f32_16x16x32_bf16(a1, b, acc2[1][ct], 0, 0, 0);
        }
    }
    float bv[8];
    #pragma unroll
    for (int ct = 0; ct < 8; ++ct) bv[ct] = bmsg[ct * 16 + n16];
    #pragma unroll
    for (int rt = 0; rt < 2; ++rt) {
        #pragma unroll
        for (int r = 0; r < 4; ++r) {
            int lrow = rbase + rt * 16 + quad * 4 + r;
            size_t grow = (size_t)bx * 128 + lrow;
            #pragma unroll
            for (int ct = 0; ct < 8; ++ct) {
                bf16 o = (bf16)(acc2[rt][ct][r] + bv[ct]);
                M[grow * 128 + ct * 16 + n16] = o;
                MT[((grow >> 10) * 128 + ct * 16 + n16) * 1024 + (grow & 1023)] = o;
            }
        }
    }
}

template <int LAST>
__global__ __launch_bounds__(512) void adj_fused(
    const float* __restrict__ Adj, const bf16* __restrict__ MT,
    const bf16* __restrict__ Mprev,
    const float* __restrict__ Wagg, const float* __restrict__ bagg,
    const float* __restrict__ W2f,  const float* __restrict__ b2,
    const float* __restrict__ Mask,
    bf16* __restrict__ Mout, bf16* __restrict__ MTout, float* __restrict__ Out)
{
    __shared__ __align__(16) bf16 smem[4 * 128 * 64];
    __shared__ __align__(16) bf16 Ts[128 * TS_LD];
    bf16* As0 = smem;
    bf16* As1 = smem + 128 * 64;
    bf16* Bs0 = smem + 2 * 128 * 64;
    bf16* Bs1 = smem + 3 * 128 * 64;

    const int tid = threadIdx.x, bid = blockIdx.x;
    const int mt = bid >> 5, b = bid & 31;
    const float* Ag = Adj + ((size_t)b << 20) + ((size_t)mt << 17);
    const bf16*  Bg = MT  + ((size_t)b << 17);

    const int lane = tid & 63, wv = tid >> 6, n16 = lane & 15, quad = lane >> 4;
    const int wr = (wv >> 2) * 64, wc = (wv & 3) * 32;

    const int kk0 = (bid * 5 + (bid >> 5)) & 15;

    floatx4 acc[4][2];
    #pragma unroll
    for (int a = 0; a < 4; ++a)
        #pragma unroll
        for (int c = 0; c < 2; ++c) acc[a][c] = (floatx4){0.f, 0.f, 0.f, 0.f};

    float4 pa[2][2]; bf16x8 pb[2];
    auto load_regs = [&](int kk) {
        #pragma unroll
        for (int i = 0; i < 2; ++i) {
            int g = tid + i * 512, row = g >> 3, gc = g & 7;
            const float4* pA = reinterpret_cast<const float4*>(
                Ag + (size_t)row * 1024 + kk * 64 + gc * 8);
            pa[i][0] = pA[0]; pa[i][1] = pA[1];
            pb[i] = *reinterpret_cast<const bf16x8*>(Bg + (size_t)row * 1024 + kk * 64 + gc * 8);
        }
    };
    auto store_lds = [&](bf16* A, bf16* B) {
        #pragma unroll
        for (int i = 0; i < 2; ++i) {
            int g = tid + i * 512, row = g >> 3, gc = g & 7;
            *reinterpret_cast<bf16x8*>(&A[row * 64 + ((gc ^ (row & 7)) << 3)]) = cvt8(pa[i][0], pa[i][1]);
            *reinterpret_cast<bf16x8*>(&B[row * 64 + ((gc ^ (row & 7)) << 3)]) = pb[i];
        }
    };

    load_regs(kk0);
    store_lds(As0, Bs0);
    for (int p = 0; p < 16; ++p) {
        bf16* Acur = (p & 1) ? As1 : As0;
        bf16* Bcur = (p & 1) ? Bs1 : Bs0;
        bf16* Anxt = (p & 1) ? As0 : As1;
        bf16* Bnxt = (p & 1) ? Bs0 : Bs1;
        __syncthreads();
        if (p < 15) load_regs((p + 1 + kk0) & 15);
        #pragma unroll
        for (int kc = 0; kc < 2; ++kc) {
            int ko = kc * 32 + quad * 8;
            bf16x8 a[4], bb[2];
            #pragma unroll
            for (int rt = 0; rt < 4; ++rt)
                a[rt] = *reinterpret_cast<const bf16x8*>(&Acur[sw64(wr + rt * 16 + n16, ko)]);
            #pragma unroll
            for (int ct = 0; ct < 2; ++ct)
                bb[ct] = *reinterpret_cast<const bf16x8*>(&Bcur[sw64(wc + ct * 16 + n16, ko)]);
            #pragma unroll
            for (int rt = 0; rt < 4; ++rt)
                #pragma unroll
                for (int ct = 0; ct < 2; ++ct)
                    acc[rt][ct] = __builtin_amdgcn_mfma_f32_16x16x32_bf16(a[rt], bb[ct], acc[rt][ct], 0, 0, 0);
        }
        if (p < 15) store_lds(Anxt, Bnxt);
    }
    __syncthreads();

    #pragma unroll
    for (int rt = 0; rt < 4; ++rt)
        #pragma unroll
        for (int ct = 0; ct < 2; ++ct)
            #pragma unroll
            for (int r = 0; r < 4; ++r) {
                int row = wr + rt * 16 + quad * 4 + r, col = wc + ct * 16 + n16;
                Ts[row * TS_LD + col] = (bf16)acc[rt][ct][r];
            }

    bf16* Wa = smem;
    bf16* W2 = smem + 128 * 128;
    {
        const int c0 = (tid & 15) * 8;
        #pragma unroll
        for (int rr = 0; rr < 4; ++rr) {
            int r = (tid >> 4) * 4 + rr;
            const float4* p = reinterpret_cast<const float4*>(Wagg + r * 128 + c0);
            float4 v0 = p[0], v1 = p[1];
            float vv[8] = {v0.x, v0.y, v0.z, v0.w, v1.x, v1.y, v1.z, v1.w};
            #pragma unroll
            for (int j = 0; j < 8; ++j) {
                int n = c0 + j;
                Wa[n * 128 + (((r >> 3) ^ (n & 15)) << 3) + (r & 7)] = (bf16)vv[j];
            }
        }
    }
    if (LAST) {
        const float4* Wg = reinterpret_cast<const float4*>(W2f);
        #pragma unroll
        for (int i = 0; i < 4; ++i) {
            int g = tid + i * 512, row = g >> 4, gc = g & 15;
            float4 v0 = Wg[2 * g], v1 = Wg[2 * g + 1];
            *reinterpret_cast<bf16x8*>(&W2[row * 128 + ((gc ^ (row & 15)) << 3)]) = cvt8(v0, v1);
        }
    } else {
        const int c0 = (tid & 15) * 8;
        #pragma unroll
        for (int rr = 0; rr < 4; ++rr) {
            int r = (tid >> 4) * 4 + rr;
            const float4* p = reinterpret_cast<const float4*>(W2f + r * 128 + c0);
            float4 v0 = p[0], v1 = p[1];
            float vv[8] = {v0.x, v0.y, v0.z, v0.w, v1.x, v1.y, v1.z, v1.w};
            #pragma unroll
            for (int j = 0; j < 8; ++j) {
                int n = c0 + j;
                W2[n * 128 + (((r >> 3) ^ (n & 15)) << 3) + (r & 7)] = (bf16)vv[j];
            }
        }
    }
    __syncthreads();

    const int rbase = wv * 16;
    const size_t growbase = (size_t)b * 1024 + (size_t)mt * 128;
    floatx4 acc2[8];
    #pragma unroll
    for (int c = 0; c < 8; ++c) acc2[c] = (floatx4){0.f, 0.f, 0.f, 0.f};
    #pragma unroll
    for (int kc = 0; kc < 4; ++kc) {
        int k0 = kc * 32 + quad * 8;
        bf16x8 a = *reinterpret_cast<const bf16x8*>(&Ts[(rbase + n16) * TS_LD + k0]);
        #pragma unroll
        for (int ct = 0; ct < 8; ++ct) {
            bf16x8 bb = *reinterpret_cast<const bf16x8*>(&Wa[sw128(ct * 16 + n16, k0)]);
            acc2[ct] = __builtin_amdgcn_mfma_f32_16x16x32_bf16(a, bb, acc2[ct], 0, 0, 0);
        }
    }
    {
        float bva[8];
        #pragma unroll
        for (int ct = 0; ct < 8; ++ct) bva[ct] = bagg[ct * 16 + n16];
        #pragma unroll
        for (int r = 0; r < 4; ++r) {
            int row = rbase + quad * 4 + r;
            size_t grow = growbase + row;
            float u[8], ss = 0.f;
            #pragma unroll
            for (int ct = 0; ct < 8; ++ct) {
                u[ct] = fmaxf(acc2[ct][r] + bva[ct] + (float)Mprev[grow * 128 + ct * 16 + n16], 0.f);
                ss += u[ct] * u[ct];
            }
            #pragma unroll
            for (int off = 1; off < 16; off <<= 1) ss += __shfl_xor(ss, off);
            float sc = hyp_scale(ss);
            #pragma unroll
            for (int ct = 0; ct < 8; ++ct)
                Ts[row * TS_LD + ct * 16 + n16] = (bf16)(u[ct] * sc);
        }
    }

    floatx4 acc3[8];
    #pragma unroll
    for (int c = 0; c < 8; ++c) acc3[c] = (floatx4){0.f, 0.f, 0.f, 0.f};
    #pragma unroll
    for (int kc = 0; kc < 4; ++kc) {
        int k0 = kc * 32 + quad * 8;
        bf16x8 a = *reinterpret_cast<const bf16x8*>(&Ts[(rbase + n16) * TS_LD + k0]);
        #pragma unroll
        for (int ct = 0; ct < 8; ++ct) {
            bf16x8 bb = *reinterpret_cast<const bf16x8*>(&W2[sw128(ct * 16 + n16, k0)]);
            acc3[ct] = __builtin_amdgcn_mfma_f32_16x16x32_bf16(a, bb, acc3[ct], 0, 0, 0);
        }
    }
    float bv2[8];
    #pragma unroll
    for (int ct = 0; ct < 8; ++ct) bv2[ct] = b2[ct * 16 + n16];
    #pragma unroll
    for (int r = 0; r < 4; ++r) {
        int row = rbase + quad * 4 + r;
        size_t grow = growbase + row;
        if (LAST) {
            float mk = Mask[grow];
            #pragma unroll
            for (int ct = 0; ct < 8; ++ct)
                Out[grow * 128 + ct * 16 + n16] = (acc3[ct][r] + bv2[ct]) * mk;
        } else {
            #pragma unroll
            for (int ct = 0; ct < 8; ++ct) {
                bf16 o = (bf16)(acc3[ct][r] + bv2[ct]);
                Mout[grow * 128 + ct * 16 + n16] = o;
                MTout[((grow >> 10) * 128 + ct * 16 + n16) * 1024 + (grow & 1023)] = o;
            }
        }
    }
}

extern "C" void kernel_launch(void* const* d_in, const int* in_sizes, int n_in,
                              void* d_out, int out_size, void* d_ws, size_t ws_size,
                              hipStream_t stream)
{
    const float* X    = (const float*)d_in[0];   // [32,1024,128]
    const float* Adj  = (const float*)d_in[1];   // [32,1024,1024]
    const float* Mask = (const float*)d_in[2];   // [32,1024,1]
    const float* Wemb = (const float*)d_in[3];   // [128,128] (out,in)
    const float* Wmsg = (const float*)d_in[4];   // [2,128,128] (in,out)
    const float* bmsg = (const float*)d_in[5];   // [2,128]
    const float* Wagg = (const float*)d_in[6];   // [2,128,128] (in,out)
    const float* bagg = (const float*)d_in[7];   // [2,128]
    const float* Wprj = (const float*)d_in[8];   // [128,128] (out,in)
    const float* bprj = (const float*)d_in[9];   // [128]
    float* out = (float*)d_out;

    const size_t BN = 32768;
    bf16* m0   = (bf16*)d_ws;        // [BN,128]
    bf16* m0T  = m0  + BN * 128;     // MTP0
    bf16* m1   = m0T + BN * 128;     // [BN,128]
    bf16* m1T  = m1  + BN * 128;     // MTP1
    bf16* AdjB = m1T + BN * 128;     // packed bf16 Adj (67 MB)

    const size_t need = (4 * BN * 128 + (size_t)33554432) * sizeof(bf16);  // 100.7 MB

    if (ws_size >= need) {
        pack_adj<<<1024, 256, 0, stream>>>(Adj, AdjB);
        embed_msg<<<256, 256, 0, stream>>>(X, Wemb, Wmsg, bmsg, m0, m0T);
        adj_fast<0><<<512, 512, 0, stream>>>(AdjB, m0T, m0, Wagg, bagg,
                                             Wmsg + 16384, bmsg + 128, nullptr,
                                             m1, m1T, nullptr);
        adj_fast<1><<<512, 512, 0, stream>>>(AdjB, m1T, m1, Wagg + 16384, bagg + 128,
                                             Wprj, bprj, Mask,
                                             nullptr, nullptr, out);
    } else {
        embed_msg_legacy<<<256, 256, 0, stream>>>(X, Wemb, Wmsg, bmsg, m0, m0T);
        adj_fused<0><<<256, 512, 0, stream>>>(Adj, m0T, m0, Wagg, bagg,
                                              Wmsg + 16384, bmsg + 128, nullptr,
                                              m1, m1T, nullptr);
        adj_fused<1><<<256, 512, 0, stream>>>(Adj, m1T, m1, Wagg + 16384, bagg + 128,
                                              Wprj, bprj, Mask,
                                              nullptr, nullptr, out);
    }
}

// Round 9
// 300.845 us; speedup vs baseline: 1.1161x; 1.1161x over previous
//
#include <hip/hip_runtime.h>
#include <hip/hip_bf16.h>

typedef __bf16 bf16;
typedef __bf16 bf16x8 __attribute__((ext_vector_type(8)));
typedef float  floatx4 __attribute__((ext_vector_type(4)));

#define EPSF    1e-7f
#define MAXNORM 0.99999f   // (1 - 1e-5) / sqrt(C), C = 1
#define TS_LD   136        // padded leading dim for LDS intermediate tile

// rowwise scale implementing logmap0(proj(expmap0(h))) = scale(||h||) * h
__device__ __forceinline__ float hyp_scale(float ss) {
    float n  = sqrtf(ss);
    float nh = fmaxf(n, EPSF);
    float s1 = tanhf(nh) / nh;
    float nx = s1 * n;
    if (nx > MAXNORM) { s1 *= MAXNORM / nx; nx = MAXNORM; }
    float nx2 = fmaxf(nx, EPSF);
    return (atanhf(nx2) / nx2) * s1;
}

__device__ __forceinline__ bf16x8 cvt8(float4 a, float4 b) {
    bf16x8 r;
    r[0] = (bf16)a.x; r[1] = (bf16)a.y; r[2] = (bf16)a.z; r[3] = (bf16)a.w;
    r[4] = (bf16)b.x; r[5] = (bf16)b.y; r[6] = (bf16)b.z; r[7] = (bf16)b.w;
    return r;
}

// XOR-granule swizzles (16B granules, conflict-free MFMA frag reads)
__device__ __forceinline__ int sw128(int row, int k) {
    return row * 128 + (((k >> 3) ^ (row & 15)) << 3) + (k & 7);
}
__device__ __forceinline__ int sw64(int row, int k) {
    return row * 64 + (((k >> 3) ^ (row & 7)) << 3) + (k & 7);
}

// async 16B global->LDS. LDS dest is wave-uniform base; HW appends lane*16.
__device__ __forceinline__ void gl_lds16(const void* g, void* l) {
    __builtin_amdgcn_global_load_lds(
        (__attribute__((address_space(1))) unsigned int*)(g),
        (__attribute__((address_space(3))) unsigned int*)(l), 16, 0, 0);
}

// ---------------------------------------------------------------------------
// MTP layout: granule G = ((b*16 + kk)*128 + n)*8 + gp (16B, n-major), holding
// m[node = kk*64 + (gp^(n&7))*8 + j][dim = n], j=0..7.  Linear gl_lds of a
// (b,kk)-tile reproduces exactly the sw64 LDS image the B-MFMA reads expect.
// Producers build it via a dim-major node-XOR-swizzled LDS tile (verified
// R5/R6): vector LDS reads + fully coalesced 16B global stores.
// ---------------------------------------------------------------------------

// ---------------------------------------------------------------------------
// K1: embed + msg0 fused.  Per block: 128 rows.  (verified R6, unchanged)
// ---------------------------------------------------------------------------
__global__ __launch_bounds__(256) void embed_msg(
    const float* __restrict__ X, const float* __restrict__ Wemb,
    const float* __restrict__ Wmsg, const float* __restrict__ bmsg,
    bf16* __restrict__ M, bf16* __restrict__ MT)
{
    __shared__ __align__(16) bf16 Xs[128 * 128];
    __shared__ __align__(16) bf16 Ws[128 * 128];
    __shared__ __align__(16) bf16 W2[128 * 128];   // reused as Ts2 after phase 2
    __shared__ __align__(16) bf16 Ts[128 * TS_LD];
    const int tid = threadIdx.x, bx = blockIdx.x;

    {
        const float4* Xg = reinterpret_cast<const float4*>(X + (size_t)bx * 16384);
        #pragma unroll
        for (int i = 0; i < 8; ++i) {
            int g = tid + i * 256, row = g >> 4, gc = g & 15;
            float4 v0 = Xg[2 * g], v1 = Xg[2 * g + 1];
            *reinterpret_cast<bf16x8*>(&Xs[row * 128 + ((gc ^ (row & 15)) << 3)]) = cvt8(v0, v1);
        }
    }
    {
        const float4* Wg = reinterpret_cast<const float4*>(Wemb);
        #pragma unroll
        for (int i = 0; i < 8; ++i) {
            int g = tid + i * 256, row = g >> 4, gc = g & 15;
            float4 v0 = Wg[2 * g], v1 = Wg[2 * g + 1];
            *reinterpret_cast<bf16x8*>(&Ws[row * 128 + ((gc ^ (row & 15)) << 3)]) = cvt8(v0, v1);
        }
    }
    {
        const int c0 = (tid & 15) * 8;
        #pragma unroll
        for (int rr = 0; rr < 8; ++rr) {
            int r = (tid >> 4) * 8 + rr;
            const float4* p = reinterpret_cast<const float4*>(Wmsg + r * 128 + c0);
            float4 v0 = p[0], v1 = p[1];
            float vv[8] = {v0.x, v0.y, v0.z, v0.w, v1.x, v1.y, v1.z, v1.w};
            #pragma unroll
            for (int j = 0; j < 8; ++j) {
                int n = c0 + j;
                W2[n * 128 + (((r >> 3) ^ (n & 15)) << 3) + (r & 7)] = (bf16)vv[j];
            }
        }
    }
    __syncthreads();

    const int lane = tid & 63, wv = tid >> 6, n16 = lane & 15, quad = lane >> 4;
    const int rbase = wv * 32;

    floatx4 acc[2][8];
    #pragma unroll
    for (int a = 0; a < 2; ++a)
        #pragma unroll
        for (int c = 0; c < 8; ++c) acc[a][c] = (floatx4){0.f, 0.f, 0.f, 0.f};
    #pragma unroll
    for (int kc = 0; kc < 4; ++kc) {
        int k0 = kc * 32 + quad * 8;
        bf16x8 a0 = *reinterpret_cast<const bf16x8*>(&Xs[sw128(rbase + n16, k0)]);
        bf16x8 a1 = *reinterpret_cast<const bf16x8*>(&Xs[sw128(rbase + 16 + n16, k0)]);
        #pragma unroll
        for (int ct = 0; ct < 8; ++ct) {
            bf16x8 b = *reinterpret_cast<const bf16x8*>(&Ws[sw128(ct * 16 + n16, k0)]);
            acc[0][ct] = __builtin_amdgcn_mfma_f32_16x16x32_bf16(a0, b, acc[0][ct], 0, 0, 0);
            acc[1][ct] = __builtin_amdgcn_mfma_f32_16x16x32_bf16(a1, b, acc[1][ct], 0, 0, 0);
        }
    }
    #pragma unroll
    for (int rt = 0; rt < 2; ++rt) {
        #pragma unroll
        for (int r = 0; r < 4; ++r) {
            int row = rbase + rt * 16 + quad * 4 + r;
            float u[8], ss = 0.f;
            #pragma unroll
            for (int ct = 0; ct < 8; ++ct) { u[ct] = acc[rt][ct][r]; ss += u[ct] * u[ct]; }
            #pragma unroll
            for (int off = 1; off < 16; off <<= 1) ss += __shfl_xor(ss, off);
            float sc = hyp_scale(ss);
            #pragma unroll
            for (int ct = 0; ct < 8; ++ct)
                Ts[row * TS_LD + ct * 16 + n16] = (bf16)(u[ct] * sc);
        }
    }
    __syncthreads();

    floatx4 acc2[2][8];
    #pragma unroll
    for (int a = 0; a < 2; ++a)
        #pragma unroll
        for (int c = 0; c < 8; ++c) acc2[a][c] = (floatx4){0.f, 0.f, 0.f, 0.f};
    #pragma unroll
    for (int kc = 0; kc < 4; ++kc) {
        int k0 = kc * 32 + quad * 8;
        bf16x8 a0 = *reinterpret_cast<const bf16x8*>(&Ts[(rbase + n16) * TS_LD + k0]);
        bf16x8 a1 = *reinterpret_cast<const bf16x8*>(&Ts[(rbase + 16 + n16) * TS_LD + k0]);
        #pragma unroll
        for (int ct = 0; ct < 8; ++ct) {
            bf16x8 b = *reinterpret_cast<const bf16x8*>(&W2[sw128(ct * 16 + n16, k0)]);
            acc2[0][ct] = __builtin_amdgcn_mfma_f32_16x16x32_bf16(a0, b, acc2[0][ct], 0, 0, 0);
            acc2[1][ct] = __builtin_amdgcn_mfma_f32_16x16x32_bf16(a1, b, acc2[1][ct], 0, 0, 0);
        }
    }
    float bv[8];
    #pragma unroll
    for (int ct = 0; ct < 8; ++ct) bv[ct] = bmsg[ct * 16 + n16];
    // pass 1: M row-major from regs (acc2 stays live across the barrier)
    #pragma unroll
    for (int rt = 0; rt < 2; ++rt) {
        #pragma unroll
        for (int r = 0; r < 4; ++r) {
            int lrow = rbase + rt * 16 + quad * 4 + r;
            size_t grow = (size_t)bx * 128 + lrow;
            #pragma unroll
            for (int ct = 0; ct < 8; ++ct)
                M[grow * 128 + ct * 16 + n16] = (bf16)(acc2[rt][ct][r] + bv[ct]);
        }
    }
    __syncthreads();                 // all phase-2 W2 reads done; W2 -> Ts2
    bf16* Ts2 = W2;                  // [128 dims][128 nodes], node XOR-swizzled
    #pragma unroll
    for (int rt = 0; rt < 2; ++rt) {
        #pragma unroll
        for (int r = 0; r < 4; ++r) {
            int lrow = rbase + rt * 16 + quad * 4 + r;
            #pragma unroll
            for (int ct = 0; ct < 8; ++ct) {
                int dim = ct * 16 + n16;
                Ts2[dim * 128 + (lrow ^ ((dim & 7) << 3))] = (bf16)(acc2[rt][ct][r] + bv[ct]);
            }
        }
    }
    __syncthreads();
    // MTP emission: 2048 granules; lane = linear granule -> contiguous 16B LDS
    // reads and fully coalesced stores.  Block owns kk tiles {mt*2, mt*2+1}.
    {
        const size_t tb = (((size_t)(bx >> 3) * 16 + (size_t)(bx & 7) * 2) << 10);
        #pragma unroll
        for (int i = 0; i < 8; ++i) {
            int g = i * 256 + tid;
            int gp = g & 7, n = (g >> 3) & 127, kkl = g >> 10;
            bf16x8 v = *reinterpret_cast<const bf16x8*>(&Ts2[n * 128 + kkl * 64 + gp * 8]);
            *reinterpret_cast<bf16x8*>(MT + ((tb + (size_t)g) << 3)) = v;
        }
    }
}

// ---------------------------------------------------------------------------
// adj_fast v4 (compile-fixed): verified-wins-only combination.
//  - A: fp32 Adj reg-staged (R0's verified dbuf sync, kk0 stagger) — no pack.
//  - B: contiguous gl_lds from MTP into linear LDS (verified R5/R6).
//  - 64-row blocks, grid 512, 66.5 KB LDS -> 2 blocks/CU (verified R5/R6).
//  - Epilogue byte-identical to verified R5/R6 version.
// LDS slot pointers computed by arithmetic (no pointer arrays — hipcc tried
// to emit the array initializer as a static addrspacecast and failed).
// Plain __syncthreads per phase drains the async B loads (compiler emits
// vmcnt(0) before s_barrier), so reg-staged A and async B mix safely.
// ---------------------------------------------------------------------------
template <int LAST>
__global__ __launch_bounds__(512) void adj_fast(
    const float* __restrict__ Adj, const bf16* __restrict__ MT,
    const bf16* __restrict__ Mprev,
    const float* __restrict__ Wagg, const float* __restrict__ bagg,
    const float* __restrict__ W2f,  const float* __restrict__ b2,
    const float* __restrict__ Mask,
    bf16* __restrict__ Mout, bf16* __restrict__ MTout, float* __restrict__ Out)
{
    __shared__ __align__(16) bf16 smem[33280];    // 66.5 KB total
    // K-loop slots (computed, not pointer arrays):
    //   A slot s: smem + s*4096        (64x64 bf16)
    //   B slot s: smem + 8192 + s*8192 (8192-elem MTP image)

    const int tid = threadIdx.x, bid = blockIdx.x;
    const int h = bid >> 8, inner = bid & 255;
    const int mt = inner >> 5, b = inner & 31;
    const float* Ag = Adj + ((size_t)b << 20) + ((size_t)mt << 17) + ((size_t)h << 16);
    const bf16*  Bg = MT + ((size_t)b << 17);     // MTP batch tile (16 x 8192)

    const int lane = tid & 63, wv = tid >> 6, n16 = lane & 15, quad = lane >> 4;
    const int wr = (wv >> 2) * 32, wc = (wv & 3) * 32;   // wave = 32 rows x 32 dims

    const int kk0 = (bid * 5 + (bid >> 5)) & 15;  // per-block K phase stagger

    floatx4 acc[2][2];
    #pragma unroll
    for (int a = 0; a < 2; ++a)
        #pragma unroll
        for (int c = 0; c < 2; ++c) acc[a][c] = (floatx4){0.f, 0.f, 0.f, 0.f};

    // A: 64 rows x 64 cols fp32 -> one (float4,float4) per thread
    const int arow = tid >> 3, agc = tid & 7;
    float4 pa0, pa1;
    auto load_regs = [&](int kk) {
        const float4* pA = reinterpret_cast<const float4*>(
            Ag + (size_t)arow * 1024 + kk * 64 + agc * 8);
        pa0 = pA[0]; pa1 = pA[1];
    };
    auto store_lds = [&](int slot) {
        bf16* A = smem + slot * 4096;
        *reinterpret_cast<bf16x8*>(&A[arow * 64 + ((agc ^ (arow & 7)) << 3)]) = cvt8(pa0, pa1);
    };
    // B: 1024 granules per kk-tile, contiguous async copy (2 insts/wave)
    auto stage_b = [&](int kk, int slot) {
        const bf16* bt = Bg + ((size_t)kk << 13);
        bf16* Bdst = smem + 8192 + slot * 8192;
        #pragma unroll
        for (int j = 0; j < 2; ++j) {
            int base = wv * 128 + j * 64;             // wave-uniform granule base
            gl_lds16(bt + (size_t)(base + lane) * 8, Bdst + base * 8);
        }
    };

    // prologue: stage logical step kk0 into slot 0
    load_regs(kk0);
    stage_b(kk0, 0);
    store_lds(0);
    for (int p = 0; p < 16; ++p) {
        const bf16* Acur = smem + (p & 1) * 4096;
        const bf16* Bcur = smem + 8192 + (p & 1) * 8192;
        __syncthreads();                      // staged buffers visible (vmcnt drained)
        if (p < 15) {
            int nk = (p + 1 + kk0) & 15;
            load_regs(nk);                    // fp32 A -> regs (overlaps MFMA)
            stage_b(nk, (p + 1) & 1);         // async B -> next LDS slot
        }
        #pragma unroll
        for (int kc = 0; kc < 2; ++kc) {
            int ko = kc * 32 + quad * 8;
            bf16x8 a[2], bb[2];
            #pragma unroll
            for (int rt = 0; rt < 2; ++rt)
                a[rt] = *reinterpret_cast<const bf16x8*>(&Acur[sw64(wr + rt * 16 + n16, ko)]);
            #pragma unroll
            for (int ct = 0; ct < 2; ++ct)
                bb[ct] = *reinterpret_cast<const bf16x8*>(&Bcur[sw64(wc + ct * 16 + n16, ko)]);
            #pragma unroll
            for (int rt = 0; rt < 2; ++rt)
                #pragma unroll
                for (int ct = 0; ct < 2; ++ct)
                    acc[rt][ct] = __builtin_amdgcn_mfma_f32_16x16x32_bf16(a[rt], bb[ct], acc[rt][ct], 0, 0, 0);
        }
        if (p < 15) store_lds((p + 1) & 1);   // other slot; reads of Acur already done
    }
    __syncthreads();   // all K-loop LDS traffic done; alias epilogue buffers

    bf16* Ts  = smem;                  // [64][TS_LD] = 8704 elems
    bf16* Wa  = smem + 8704;           // 128x128 sw128 (Wagg, then W2 over it)
    bf16* Ts2 = smem + 25088;          // [128 dims][64 nodes] swizzled (8192)

    // write agg C-tiles into padded Ts
    #pragma unroll
    for (int rt = 0; rt < 2; ++rt)
        #pragma unroll
        for (int ct = 0; ct < 2; ++ct)
            #pragma unroll
            for (int r = 0; r < 4; ++r) {
                int row = wr + rt * 16 + quad * 4 + r, col = wc + ct * 16 + n16;
                Ts[row * TS_LD + col] = (bf16)acc[rt][ct][r];
            }
    // stage Wagg [in][out] transposed -> Wa
    {
        const int c0 = (tid & 15) * 8;
        #pragma unroll
        for (int rr = 0; rr < 4; ++rr) {
            int r = (tid >> 4) * 4 + rr;
            const float4* p = reinterpret_cast<const float4*>(Wagg + r * 128 + c0);
            float4 v0 = p[0], v1 = p[1];
            float vv[8] = {v0.x, v0.y, v0.z, v0.w, v1.x, v1.y, v1.z, v1.w};
            #pragma unroll
            for (int j = 0; j < 8; ++j) {
                int n = c0 + j;
                Wa[n * 128 + (((r >> 3) ^ (n & 15)) << 3) + (r & 7)] = (bf16)vv[j];
            }
        }
    }
    __syncthreads();

    // phase 3 (waves 0-3): u = relu(agg@Wagg + bagg + m_prev); t = rowscale(u)
    const int rbase = (wv & 3) * 16;
    const size_t growbase = (size_t)b * 1024 + (size_t)mt * 128 + (size_t)h * 64;
    floatx4 acc2[8];
    #pragma unroll
    for (int c = 0; c < 8; ++c) acc2[c] = (floatx4){0.f, 0.f, 0.f, 0.f};
    if (wv < 4) {
        #pragma unroll
        for (int kc = 0; kc < 4; ++kc) {
            int k0 = kc * 32 + quad * 8;
            bf16x8 a = *reinterpret_cast<const bf16x8*>(&Ts[(rbase + n16) * TS_LD + k0]);
            #pragma unroll
            for (int ct = 0; ct < 8; ++ct) {
                bf16x8 bb = *reinterpret_cast<const bf16x8*>(&Wa[sw128(ct * 16 + n16, k0)]);
                acc2[ct] = __builtin_amdgcn_mfma_f32_16x16x32_bf16(a, bb, acc2[ct], 0, 0, 0);
            }
        }
        float bva[8];
        #pragma unroll
        for (int ct = 0; ct < 8; ++ct) bva[ct] = bagg[ct * 16 + n16];
        #pragma unroll
        for (int r = 0; r < 4; ++r) {
            int row = rbase + quad * 4 + r;
            size_t grow = growbase + row;
            float u[8], ss = 0.f;
            #pragma unroll
            for (int ct = 0; ct < 8; ++ct) {
                u[ct] = fmaxf(acc2[ct][r] + bva[ct] + (float)Mprev[grow * 128 + ct * 16 + n16], 0.f);
                ss += u[ct] * u[ct];
            }
            #pragma unroll
            for (int off = 1; off < 16; off <<= 1) ss += __shfl_xor(ss, off);
            float sc = hyp_scale(ss);
            #pragma unroll
            for (int ct = 0; ct < 8; ++ct)
                Ts[row * TS_LD + ct * 16 + n16] = (bf16)(u[ct] * sc);
        }
    }
    __syncthreads();   // Wa reads done; load W2 over it

    if (LAST) {
        const float4* Wg = reinterpret_cast<const float4*>(W2f);
        #pragma unroll
        for (int i = 0; i < 4; ++i) {
            int g = tid + i * 512, row = g >> 4, gc = g & 15;
            float4 v0 = Wg[2 * g], v1 = Wg[2 * g + 1];
            *reinterpret_cast<bf16x8*>(&Wa[row * 128 + ((gc ^ (row & 15)) << 3)]) = cvt8(v0, v1);
        }
    } else {
        const int c0 = (tid & 15) * 8;
        #pragma unroll
        for (int rr = 0; rr < 4; ++rr) {
            int r = (tid >> 4) * 4 + rr;
            const float4* p = reinterpret_cast<const float4*>(W2f + r * 128 + c0);
            float4 v0 = p[0], v1 = p[1];
            float vv[8] = {v0.x, v0.y, v0.z, v0.w, v1.x, v1.y, v1.z, v1.w};
            #pragma unroll
            for (int j = 0; j < 8; ++j) {
                int n = c0 + j;
                Wa[n * 128 + (((r >> 3) ^ (n & 15)) << 3) + (r & 7)] = (bf16)vv[j];
            }
        }
    }
    __syncthreads();

    // phase 4 (waves 0-3): t @ W2 (+b2)
    floatx4 acc3[8];
    #pragma unroll
    for (int c = 0; c < 8; ++c) acc3[c] = (floatx4){0.f, 0.f, 0.f, 0.f};
    if (wv < 4) {
        #pragma unroll
        for (int kc = 0; kc < 4; ++kc) {
            int k0 = kc * 32 + quad * 8;
            bf16x8 a = *reinterpret_cast<const bf16x8*>(&Ts[(rbase + n16) * TS_LD + k0]);
            #pragma unroll
            for (int ct = 0; ct < 8; ++ct) {
                bf16x8 bb = *reinterpret_cast<const bf16x8*>(&Wa[sw128(ct * 16 + n16, k0)]);
                acc3[ct] = __builtin_amdgcn_mfma_f32_16x16x32_bf16(a, bb, acc3[ct], 0, 0, 0);
            }
        }
        float bv2[8];
        #pragma unroll
        for (int ct = 0; ct < 8; ++ct) bv2[ct] = b2[ct * 16 + n16];
        #pragma unroll
        for (int r = 0; r < 4; ++r) {
            int row = rbase + quad * 4 + r;
            size_t grow = growbase + row;
            if (LAST) {
                float mk = Mask[grow];
                #pragma unroll
                for (int ct = 0; ct < 8; ++ct)
                    Out[grow * 128 + ct * 16 + n16] = (acc3[ct][r] + bv2[ct]) * mk;
            } else {
                #pragma unroll
                for (int ct = 0; ct < 8; ++ct) {
                    int dim = ct * 16 + n16;
                    bf16 o = (bf16)(acc3[ct][r] + bv2[ct]);
                    Mout[grow * 128 + dim] = o;
                    Ts2[dim * 64 + (row ^ ((dim & 7) << 3))] = o;
                }
            }
        }
    }
    if (!LAST) {
        __syncthreads();
        // MTP emission: this half-block owns kk-tile (mt*2 + h) of batch b.
        const size_t tb = (((size_t)b * 16 + (size_t)(mt * 2 + h)) << 10);
        #pragma unroll
        for (int i = 0; i < 2; ++i) {
            int g = i * 512 + tid;
            int gp = g & 7, n = g >> 3;
            bf16x8 v = *reinterpret_cast<const bf16x8*>(&Ts2[n * 64 + gp * 8]);
            *reinterpret_cast<bf16x8*>(MTout + ((tb + (size_t)g) << 3)) = v;
        }
    }
}

extern "C" void kernel_launch(void* const* d_in, const int* in_sizes, int n_in,
                              void* d_out, int out_size, void* d_ws, size_t ws_size,
                              hipStream_t stream)
{
    const float* X    = (const float*)d_in[0];   // [32,1024,128]
    const float* Adj  = (const float*)d_in[1];   // [32,1024,1024]
    const float* Mask = (const float*)d_in[2];   // [32,1024,1]
    const float* Wemb = (const float*)d_in[3];   // [128,128] (out,in)
    const float* Wmsg = (const float*)d_in[4];   // [2,128,128] (in,out)
    const float* bmsg = (const float*)d_in[5];   // [2,128]
    const float* Wagg = (const float*)d_in[6];   // [2,128,128] (in,out)
    const float* bagg = (const float*)d_in[7];   // [2,128]
    const float* Wprj = (const float*)d_in[8];   // [128,128] (out,in)
    const float* bprj = (const float*)d_in[9];   // [128]
    float* out = (float*)d_out;

    const size_t BN = 32768;
    bf16* m0   = (bf16*)d_ws;        // [BN,128] row-major
    bf16* m0T  = m0  + BN * 128;     // MTP0 [32][16][128][8] granules
    bf16* m1   = m0T + BN * 128;     // [BN,128]
    bf16* m1T  = m1  + BN * 128;     // MTP1

    embed_msg<<<256, 256, 0, stream>>>(X, Wemb, Wmsg, bmsg, m0, m0T);
    adj_fast<0><<<512, 512, 0, stream>>>(Adj, m0T, m0, Wagg, bagg,
                                         Wmsg + 16384, bmsg + 128, nullptr,
                                         m1, m1T, nullptr);
    adj_fast<1><<<512, 512, 0, stream>>>(Adj, m1T, m1, Wagg + 16384, bagg + 128,
                                         Wprj, bprj, Mask,
                                         nullptr, nullptr, out);
}